// Round 13
// baseline (3169.815 us; speedup 1.0000x reference)
//
#include <hip/hip_runtime.h>

typedef unsigned int u32;
typedef unsigned short u16;
typedef __attribute__((ext_vector_type(8))) short short8;
typedef __attribute__((ext_vector_type(4))) float floatx4;

#define L2E  1.44269504088896340736f
#define L2E2 2.88539008177792681472f

static __device__ __forceinline__ u16 f2bf(float f){
  u32 u = __float_as_uint(f);
  u = (u + 0x7FFFu + ((u >> 16) & 1u)) >> 16;
  return (u16)u;
}
static __device__ __forceinline__ u32 pk2bf(float lo, float hi){
  u32 r; asm("v_cvt_pk_bf16_f32 %0, %1, %2" : "=v"(r) : "v"(lo), "v"(hi)); return r;
}
static __device__ __forceinline__ float rcp_(float x){ return __builtin_amdgcn_rcpf(x); }
static __device__ __forceinline__ float exp2_(float x){ return __builtin_amdgcn_exp2f(x); }
static __device__ __forceinline__ float sigm2(float yh){ return rcp_(1.f + exp2_(-yh)); }   // log2e folded
static __device__ __forceinline__ float tanh2(float yh2){ return 1.f - 2.f*rcp_(1.f + exp2_(yh2)); } // 2*log2e folded

// ---- prep: weights -> flat slice-major MFMA B-frag order, bf16, log2e-prescaled ----
// dst[s*8192 + (g*4+c)*512 + L*8 + j] = W[g*128 + s*16 + (L&15)][c*32 + (L>>4)*8 + j] * scale
__global__ __launch_bounds__(256) void prep_weights(
    const float* eWhh0, const float* eWhh1, const float* eWih1,
    const float* dWhh0, const float* dWhh1, const float* dWih1,
    u16* wE0, u16* wE1h, u16* wE1x, u16* wD0, u16* wD1h, u16* wD1x)
{
  int idx = blockIdx.x * 256 + threadIdx.x;   // 6*65536
  int m = idx >> 16, e = idx & 65535;
  int j = e & 7, L = (e >> 3) & 63, c = (e >> 9) & 3, g = (e >> 11) & 3, s = (e >> 13) & 7;
  int row = g*128 + s*16 + (L & 15);
  int col = c*32 + ((L >> 4) * 8) + j;
  float scale = (g == 2) ? L2E2 : L2E;
  const float* src; u16* dst;
  switch(m){
    case 0: src = eWhh0; dst = wE0;  break;
    case 1: src = eWhh1; dst = wE1h; break;
    case 2: src = eWih1; dst = wE1x; break;
    case 3: src = dWhh0; dst = wD0;  break;
    case 4: src = dWhh1; dst = wD1h; break;
    default:src = dWih1; dst = wD1x; break;
  }
  dst[e] = f2bf(src[row*128 + col] * scale);
}

__global__ __launch_bounds__(256) void prep_small(
    const float* ebih0,const float* ebhh0,const float* ebih1,const float* ebhh1,
    const float* dbih0,const float* dbhh0,const float* dbih1,const float* dbhh1,
    const float* eWih0,const float* dWih0, float* biasAll, float* wxAll)
{
  int i = blockIdx.x*256 + threadIdx.x;    // 4096
  if (i < 2048){
    int l = i >> 9, n = i & 511, g = (n >> 7) & 3;
    const float* a = l==0?ebih0: l==1?ebih1: l==2?dbih0: dbih1;
    const float* b = l==0?ebhh0: l==1?ebhh1: l==2?dbhh0: dbhh1;
    biasAll[i] = (a[n] + b[n]) * ((g==2)? L2E2 : L2E);
  } else {
    int k = i - 2048;                       // 2 x 1024
    int l = k >> 10, e2 = k & 1023, n = e2 >> 1, g = (n >> 7) & 3;
    const float* wsrc = l ? dWih0 : eWih0;
    wxAll[k] = wsrc[e2] * ((g==2)? L2E2 : L2E);
  }
}

// ---- pairwise sync: wave w <-> partner wp (= w^1). -------------------------
// Release: drain own LDS writes (lgkmcnt), lane0 publishes epoch.
// Acquire: poll partner's epoch (LDS broadcast read), then fence code motion.
static __device__ __forceinline__ void pair_sync(
    volatile int* sig, int w, int wp, int e, int lane)
{
  asm volatile("s_waitcnt lgkmcnt(0)" ::: "memory");
  if (lane == 0) sig[w] = e;
  while (sig[wp] < e) __builtin_amdgcn_s_sleep(2);
  asm volatile("" ::: "memory");
  __builtin_amdgcn_sched_barrier(0);
}

// =======================================================================
// R8/R10 per-wave math, re-tiled for 3 blocks/CU occupancy.
// 64-sample / 4-wave / 256-thread blocks: per-block LDS ~50KB -> 3
// blocks/CU = 12 waves/CU = 3 waves/SIMD at 128 VGPR (384/512 pool, no
// spill; R3's failure was launch_bounds(512,4) forcing a 64-VGPR cap —
// here launch_bounds(256,3) caps at 170 >= the 128 the code uses).
// Each SIMD hosts 3 waves from 3 mutually-unsynchronized blocks ->
// natural anti-phase replaces R10's hand-tuned skew: one wave's
// MFMA/nonlin covers another's load/handshake stalls, raising VALU-pipe
// utilization (the measured bottleneck: 640 quarter-rate trans ops/wave/
// step). Pairs (0,1),(2,3); pairwise handshakes as in R8.
// R11 bug fixed: sFc init is a strided loop (256-thread blocks left
// sFc[256..257] = FC bias uninitialized -> absmax 47).
// R12 was an infra failure (container), not a kernel result — rerun.
// =======================================================================
template<bool DEC>
static __device__ __forceinline__ void step_t(
    int w, int wp, int grp, int mtb, int lane, int n4, int q, int m0, int t,
    u16* h0s, u16* h1s, float* fcp, volatile int* sig0, volatile int* sig1,
    const float* sB, const float* sWx, const float* sFc,
    const u16* __restrict__ W0, const u16* __restrict__ W1h,
    const u16* __restrict__ W1x,
    short8 (&ah)[2][4], float2 (&xc)[2][4],
    floatx4 (&c0a)[2][4], floatx4 (&c1a)[2][4],
    float* __restrict__ out)
{
  const int bofs = DEC ? 1024 : 0;
  const int wxo  = DEC ? 512  : 0;
  const int lb = lane * 8;
  const int epoch = t + 1;

  // h1_old A-frags (own 2 mtiles, full K). Must be read before the flag0
  // signal: partner's h1 writes of this step are gated by our flag0.
  short8 a1[2][4];
  #pragma unroll
  for (int j = 0; j < 2; j++)
    #pragma unroll
    for (int c = 0; c < 4; c++)
      a1[j][c] = *(const short8*)(h1s + ((mtb+j)*4 + c)*512 + lb);

  // ---------------- cell 0: 4 slices (own N-half) ----------------------
  #pragma unroll 1
  for (int i = 0; i < 4; i++){
    const int s = grp*4 + i;
    const u16* bs = W0 + s*8192;
    short8 bw[16];
    #pragma unroll
    for (int k = 0; k < 16; k++)
      bw[k] = *(const short8*)(bs + k*512 + lb);
    floatx4 acc[4][2];
    #pragma unroll
    for (int g = 0; g < 4; g++){
      float bi = sB[bofs + g*128 + s*16 + n4];
      float2 wv = ((const float2*)sWx)[wxo + g*128 + s*16 + n4];
      #pragma unroll
      for (int j = 0; j < 2; j++)
        #pragma unroll
        for (int r = 0; r < 4; r++)
          acc[g][j][r] = fmaf(xc[j][r].y, wv.y, fmaf(xc[j][r].x, wv.x, bi));
    }
    __builtin_amdgcn_s_setprio(1);
    #pragma unroll
    for (int c = 0; c < 4; c++)
      #pragma unroll
      for (int g = 0; g < 4; g++){
        acc[g][0] = __builtin_amdgcn_mfma_f32_16x16x32_bf16(ah[0][c], bw[g*4+c], acc[g][0], 0,0,0);
        acc[g][1] = __builtin_amdgcn_mfma_f32_16x16x32_bf16(ah[1][c], bw[g*4+c], acc[g][1], 0,0,0);
      }
    __builtin_amdgcn_s_setprio(0);
    #pragma unroll
    for (int j = 0; j < 2; j++){
      const int hb = ((mtb+j)*4 + (s>>1))*512 + ((s&1)*2 + (n4>>3))*128 + q*32 + (n4&7);
      floatx4 cc = c0a[j][i], cn;
      float hv[4];
      #pragma unroll
      for (int r = 0; r < 4; r++){
        float ig = sigm2(acc[0][j][r]);
        float fg = sigm2(acc[1][j][r]);
        float gg = tanh2(acc[2][j][r]);
        float cv = fmaf(fg, cc[r], ig*gg);
        float og = sigm2(acc[3][j][r]);
        hv[r] = og * (1.f - 2.f*rcp_(1.f + exp2_(L2E2*cv)));
        cn[r] = cv;
      }
      u32 p01 = pk2bf(hv[0], hv[1]), p23 = pk2bf(hv[2], hv[3]);
      h0s[hb +  0] = (u16)p01;
      h0s[hb +  8] = (u16)(p01 >> 16);
      h0s[hb + 16] = (u16)p23;
      h0s[hb + 24] = (u16)(p23 >> 16);
      c0a[j][i] = cn;
    }
  }
  pair_sync(sig0, w, wp, epoch, lane);   // h0_new pairwise handoff

  // refresh ah = h0_new (also next step's h0_old frags)
  #pragma unroll
  for (int j = 0; j < 2; j++)
    #pragma unroll
    for (int c = 0; c < 4; c++)
      ah[j][c] = *(const short8*)(h0s + ((mtb+j)*4 + c)*512 + lb);

  float p[2][4][2];
  if (DEC){
    #pragma unroll
    for (int j = 0; j < 2; j++)
      #pragma unroll
      for (int r = 0; r < 4; r++){ p[j][r][0] = 0.f; p[j][r][1] = 0.f; }
  }

  // ---------------- cell 1: per slice, W1h x a1 then W1x x h0_new -------
  #pragma unroll 1
  for (int i = 0; i < 4; i++){
    const int s = grp*4 + i;
    floatx4 acc[4][2];
    #pragma unroll
    for (int g = 0; g < 4; g++){
      float bi = sB[bofs + 512 + g*128 + s*16 + n4];
      #pragma unroll
      for (int j = 0; j < 2; j++)
        #pragma unroll
        for (int r = 0; r < 4; r++) acc[g][j][r] = bi;
    }
    {
      const u16* bs = W1h + s*8192;
      short8 bw[16];
      #pragma unroll
      for (int k = 0; k < 16; k++)
        bw[k] = *(const short8*)(bs + k*512 + lb);
      __builtin_amdgcn_s_setprio(1);
      #pragma unroll
      for (int c = 0; c < 4; c++)
        #pragma unroll
        for (int g = 0; g < 4; g++){
          acc[g][0] = __builtin_amdgcn_mfma_f32_16x16x32_bf16(a1[0][c], bw[g*4+c], acc[g][0], 0,0,0);
          acc[g][1] = __builtin_amdgcn_mfma_f32_16x16x32_bf16(a1[1][c], bw[g*4+c], acc[g][1], 0,0,0);
        }
      __builtin_amdgcn_s_setprio(0);
    }
    {
      const u16* bs = W1x + s*8192;
      short8 bw[16];
      #pragma unroll
      for (int k = 0; k < 16; k++)
        bw[k] = *(const short8*)(bs + k*512 + lb);
      __builtin_amdgcn_s_setprio(1);
      #pragma unroll
      for (int c = 0; c < 4; c++)
        #pragma unroll
        for (int g = 0; g < 4; g++){
          acc[g][0] = __builtin_amdgcn_mfma_f32_16x16x32_bf16(ah[0][c], bw[g*4+c], acc[g][0], 0,0,0);
          acc[g][1] = __builtin_amdgcn_mfma_f32_16x16x32_bf16(ah[1][c], bw[g*4+c], acc[g][1], 0,0,0);
        }
      __builtin_amdgcn_s_setprio(0);
    }
    float f0 = 0.f, f1 = 0.f;
    if (DEC){ f0 = sFc[s*16 + n4]; f1 = sFc[128 + s*16 + n4]; }
    #pragma unroll
    for (int j = 0; j < 2; j++){
      const int hb = ((mtb+j)*4 + (s>>1))*512 + ((s&1)*2 + (n4>>3))*128 + q*32 + (n4&7);
      floatx4 cc = c1a[j][i], cn;
      float hv[4];
      #pragma unroll
      for (int r = 0; r < 4; r++){
        float ig = sigm2(acc[0][j][r]);
        float fg = sigm2(acc[1][j][r]);
        float gg = tanh2(acc[2][j][r]);
        float cv = fmaf(fg, cc[r], ig*gg);
        float og = sigm2(acc[3][j][r]);
        hv[r] = og * (1.f - 2.f*rcp_(1.f + exp2_(L2E2*cv)));
        cn[r] = cv;
        if (DEC){
          p[j][r][0] = fmaf(hv[r], f0, p[j][r][0]);
          p[j][r][1] = fmaf(hv[r], f1, p[j][r][1]);
        }
      }
      u32 p01 = pk2bf(hv[0], hv[1]), p23 = pk2bf(hv[2], hv[3]);
      h1s[hb +  0] = (u16)p01;
      h1s[hb +  8] = (u16)(p01 >> 16);
      h1s[hb + 16] = (u16)p23;
      h1s[hb + 24] = (u16)(p23 >> 16);
      c1a[j][i] = cn;
    }
  }

  if (DEC){
    // butterfly over n4 (16 lanes) -> per-group partial; stash pre-handshake
    #pragma unroll
    for (int off = 1; off < 16; off <<= 1)
      #pragma unroll
      for (int j = 0; j < 2; j++)
        #pragma unroll
        for (int r = 0; r < 4; r++){
          p[j][r][0] += __shfl_xor(p[j][r][0], off);
          p[j][r][1] += __shfl_xor(p[j][r][1], off);
        }
    if (n4 == 0){
      #pragma unroll
      for (int j = 0; j < 2; j++)
        #pragma unroll
        for (int r = 0; r < 4; r++){
          const int base = ((mtb+j)*16 + q*4 + r)*4 + grp*2;
          fcp[base + 0] = p[j][r][0];
          fcp[base + 1] = p[j][r][1];
        }
    }
  }
  pair_sync(sig1, w, wp, epoch, lane);   // h1_new + fcp pairwise handoff

  if (DEC){
    const float fb0 = sFc[256], fb1 = sFc[257];
    #pragma unroll
    for (int j = 0; j < 2; j++)
      #pragma unroll
      for (int r = 0; r < 4; r++){
        const int base = ((mtb+j)*16 + q*4 + r)*4;
        float2 pv;
        pv.x = fcp[base + 0] + fcp[base + 2] + fb0;
        pv.y = fcp[base + 1] + fcp[base + 3] + fb1;
        xc[j][r] = pv;
        if (grp == 0 && n4 == 0)
          *(float2*)(out + (long)(m0 + (mtb+j)*16 + q*4 + r)*90 + (t - 20)*2) = pv;
      }
  }
}

__global__ __launch_bounds__(256, 3) void lstm_all(
    const float* __restrict__ in_seq,
    const u16* __restrict__ wE0, const u16* __restrict__ wE1h, const u16* __restrict__ wE1x,
    const u16* __restrict__ wD0, const u16* __restrict__ wD1h, const u16* __restrict__ wD1x,
    const float* __restrict__ biasAll, const float* __restrict__ wxAll,
    const float* __restrict__ fcW, const float* __restrict__ fcb,
    float* __restrict__ out)
{
  __shared__ u16 h0s[8192];      // 64 samples x 128 h, bf16
  __shared__ u16 h1s[8192];
  __shared__ float sB[2048];
  __shared__ float sWx[2048];
  __shared__ float sFc[260];
  __shared__ float fcp[256];
  __shared__ int  sig[8];        // [0..3]=flag0, [4..7]=flag1

  const int tid = threadIdx.x, lane = tid & 63, w = tid >> 6;   // w in 0..3
  const int wp  = w ^ 1;               // partner wave (within-pair sync only)
  const int grp = w & 1, mtb = (w >> 1) * 2;
  const int n4 = lane & 15, q = lane >> 4;
  const int m0 = blockIdx.x * 64;

  for (int i = tid; i < 2048; i += 256){ sB[i] = biasAll[i]; sWx[i] = wxAll[i]; }
  for (int i = tid; i < 258; i += 256) sFc[i] = (i < 256) ? fcW[i] : fcb[i - 256];
  if (tid < 8) sig[tid] = 0;
  { u32* z0 = (u32*)h0s; u32* z1 = (u32*)h1s;
    for (int i = tid; i < 4096; i += 256){ z0[i] = 0u; z1[i] = 0u; } }

  floatx4 c0a[2][4], c1a[2][4];
  const floatx4 z4 = {0.f,0.f,0.f,0.f};
  #pragma unroll
  for (int j = 0; j < 2; j++)
    #pragma unroll
    for (int i = 0; i < 4; i++){ c0a[j][i] = z4; c1a[j][i] = z4; }
  __syncthreads();

  // prime h0_old frags (zeros); barrier orders these reads before step-0
  // writes from any wave
  short8 ah[2][4];
  #pragma unroll
  for (int j = 0; j < 2; j++)
    #pragma unroll
    for (int c = 0; c < 4; c++)
      ah[j][c] = *(const short8*)(h0s + ((mtb+j)*4 + c)*512 + lane*8);
  __syncthreads();

  float2 xc[2][4];

  // -------- encoder: t = 0..19 --------
  #pragma unroll 1
  for (int t = 0; t < 20; t++){
    #pragma unroll
    for (int j = 0; j < 2; j++)
      #pragma unroll
      for (int r = 0; r < 4; r++)
        xc[j][r] = *(const float2*)(in_seq + (long)(m0 + (mtb+j)*16 + q*4 + r)*40 + t*2);
    step_t<false>(w, wp, grp, mtb, lane, n4, q, m0, t, h0s, h1s, fcp,
                  sig, sig + 4, sB, sWx, sFc,
                  wE0, wE1h, wE1x, ah, xc, c0a, c1a, out);
  }

  // -------- decoder: t = 20..64, x fed back in registers --------
  #pragma unroll
  for (int j = 0; j < 2; j++)
    #pragma unroll
    for (int r = 0; r < 4; r++)
      xc[j][r] = *(const float2*)(in_seq + (long)(m0 + (mtb+j)*16 + q*4 + r)*40 + 38);

  #pragma unroll 1
  for (int t = 20; t < 65; t++){
    step_t<true>(w, wp, grp, mtb, lane, n4, q, m0, t, h0s, h1s, fcp,
                 sig, sig + 4, sB, sWx, sFc,
                 wD0, wD1h, wD1x, ah, xc, c0a, c1a, out);
  }
}

// ---------------- host ----------------
extern "C" void kernel_launch(void* const* d_in, const int* in_sizes, int n_in,
                              void* d_out, int out_size, void* d_ws, size_t ws_size,
                              hipStream_t stream)
{
  const float* in_seq = (const float*)d_in[0];
  const float* eWih0 = (const float*)d_in[1];
  const float* eWhh0 = (const float*)d_in[2];
  const float* ebih0 = (const float*)d_in[3];
  const float* ebhh0 = (const float*)d_in[4];
  const float* eWih1 = (const float*)d_in[5];
  const float* eWhh1 = (const float*)d_in[6];
  const float* ebih1 = (const float*)d_in[7];
  const float* ebhh1 = (const float*)d_in[8];
  const float* dWih0 = (const float*)d_in[9];
  const float* dWhh0 = (const float*)d_in[10];
  const float* dbih0 = (const float*)d_in[11];
  const float* dbhh0 = (const float*)d_in[12];
  const float* dWih1 = (const float*)d_in[13];
  const float* dWhh1 = (const float*)d_in[14];
  const float* dbih1 = (const float*)d_in[15];
  const float* dbhh1 = (const float*)d_in[16];
  const float* fcW   = (const float*)d_in[17];
  const float* fcb   = (const float*)d_in[18];
  float* out = (float*)d_out;
  char* ws = (char*)d_ws;

  u16* wE0   = (u16*)(ws + 0);                 // 128 KB each
  u16* wE1h  = (u16*)(ws + 131072);
  u16* wE1x  = (u16*)(ws + 262144);
  u16* wD0   = (u16*)(ws + 393216);
  u16* wD1h  = (u16*)(ws + 524288);
  u16* wD1x  = (u16*)(ws + 655360);
  float* biasAll = (float*)(ws + 786432);      // 8 KB
  float* wxAll   = (float*)(ws + 794624);      // 8 KB

  hipLaunchKernelGGL(prep_weights, dim3(1536), dim3(256), 0, stream,
                     eWhh0, eWhh1, eWih1, dWhh0, dWhh1, dWih1,
                     wE0, wE1h, wE1x, wD0, wD1h, wD1x);
  hipLaunchKernelGGL(prep_small, dim3(16), dim3(256), 0, stream,
                     ebih0, ebhh0, ebih1, ebhh1, dbih0, dbhh0, dbih1, dbhh1,
                     eWih0, dWih0, biasAll, wxAll);

  hipLaunchKernelGGL(lstm_all, dim3(512), dim3(256), 0, stream,
                     in_seq, (const u16*)wE0, (const u16*)wE1h, (const u16*)wE1x,
                     (const u16*)wD0, (const u16*)wD1h, (const u16*)wD1x,
                     (const float*)biasAll, (const float*)wxAll, fcW, fcb, out);
}

// Round 14
// 1334.085 us; speedup vs baseline: 2.3760x; 2.3760x over previous
//
#include <hip/hip_runtime.h>

typedef unsigned int u32;
typedef unsigned short u16;
typedef __attribute__((ext_vector_type(8))) short short8;
typedef __attribute__((ext_vector_type(4))) float floatx4;

#define L2E  1.44269504088896340736f
#define L2E2 2.88539008177792681472f

static __device__ __forceinline__ u16 f2bf(float f){
  u32 u = __float_as_uint(f);
  u = (u + 0x7FFFu + ((u >> 16) & 1u)) >> 16;
  return (u16)u;
}
static __device__ __forceinline__ u32 pk2bf(float lo, float hi){
  u32 r; asm("v_cvt_pk_bf16_f32 %0, %1, %2" : "=v"(r) : "v"(lo), "v"(hi)); return r;
}
static __device__ __forceinline__ float rcp_(float x){ return __builtin_amdgcn_rcpf(x); }
static __device__ __forceinline__ float exp2_(float x){ return __builtin_amdgcn_exp2f(x); }
static __device__ __forceinline__ float sigm2(float yh){ return rcp_(1.f + exp2_(-yh)); }   // log2e folded
static __device__ __forceinline__ float tanh2(float yh2){ return 1.f - 2.f*rcp_(1.f + exp2_(yh2)); } // 2*log2e folded

// ---- prep: weights -> flat slice-major MFMA B-frag order, bf16, log2e-prescaled ----
// dst[s*8192 + (g*4+c)*512 + L*8 + j] = W[g*128 + s*16 + (L&15)][c*32 + (L>>4)*8 + j] * scale
__global__ __launch_bounds__(256) void prep_weights(
    const float* eWhh0, const float* eWhh1, const float* eWih1,
    const float* dWhh0, const float* dWhh1, const float* dWih1,
    u16* wE0, u16* wE1h, u16* wE1x, u16* wD0, u16* wD1h, u16* wD1x)
{
  int idx = blockIdx.x * 256 + threadIdx.x;   // 6*65536
  int m = idx >> 16, e = idx & 65535;
  int j = e & 7, L = (e >> 3) & 63, c = (e >> 9) & 3, g = (e >> 11) & 3, s = (e >> 13) & 7;
  int row = g*128 + s*16 + (L & 15);
  int col = c*32 + ((L >> 4) * 8) + j;
  float scale = (g == 2) ? L2E2 : L2E;
  const float* src; u16* dst;
  switch(m){
    case 0: src = eWhh0; dst = wE0;  break;
    case 1: src = eWhh1; dst = wE1h; break;
    case 2: src = eWih1; dst = wE1x; break;
    case 3: src = dWhh0; dst = wD0;  break;
    case 4: src = dWhh1; dst = wD1h; break;
    default:src = dWih1; dst = wD1x; break;
  }
  dst[e] = f2bf(src[row*128 + col] * scale);
}

__global__ __launch_bounds__(256) void prep_small(
    const float* ebih0,const float* ebhh0,const float* ebih1,const float* ebhh1,
    const float* dbih0,const float* dbhh0,const float* dbih1,const float* dbhh1,
    const float* eWih0,const float* dWih0, float* biasAll, float* wxAll)
{
  int i = blockIdx.x*256 + threadIdx.x;    // 4096
  if (i < 2048){
    int l = i >> 9, n = i & 511, g = (n >> 7) & 3;
    const float* a = l==0?ebih0: l==1?ebih1: l==2?dbih0: dbih1;
    const float* b = l==0?ebhh0: l==1?ebhh1: l==2?dbhh0: dbhh1;
    biasAll[i] = (a[n] + b[n]) * ((g==2)? L2E2 : L2E);
  } else {
    int k = i - 2048;                       // 2 x 1024
    int l = k >> 10, e2 = k & 1023, n = e2 >> 1, g = (n >> 7) & 3;
    const float* wsrc = l ? dWih0 : eWih0;
    wxAll[k] = wsrc[e2] * ((g==2)? L2E2 : L2E);
  }
}

// ---- pairwise sync: wave w <-> partner wp (= w^1). -------------------------
// Release: drain own LDS writes (lgkmcnt), lane0 publishes epoch.
// Acquire: poll partner's epoch (LDS broadcast read), then fence code motion.
static __device__ __forceinline__ void pair_sync(
    volatile int* sig, int w, int wp, int e, int lane)
{
  asm volatile("s_waitcnt lgkmcnt(0)" ::: "memory");
  if (lane == 0) sig[w] = e;
  while (sig[wp] < e) __builtin_amdgcn_s_sleep(2);
  asm volatile("" ::: "memory");
  __builtin_amdgcn_sched_barrier(0);
}

// =======================================================================
// Best-verified configuration (R10, total 1334.7us, kernel 1457us).
// Structure: single persistent kernel; weights ring-free in L2 in MFMA
// B-frag layout; 8 waves = 4 mtile-pairs x 2 N-halves; pairwise w^1
// handshakes (2/step) instead of block barriers; setprio(1) around MFMA
// clusters; cvt_pk_bf16 h-writes; one-time ~10us cohort skew for waves
// 4..7 so each SIMD's two resident waves run anti-phase (+2.5% measured).
// Measured walls (R3/R5/R13: regalloc spill at any occupancy push;
// R9: per-XCD L2 BW at any reuse reduction; R4: barrier cost of LDS
// weight staging; R8/R10: serial h(t)->h(t+1) recurrence latency).
// =======================================================================
template<bool DEC>
static __device__ __forceinline__ void step_t(
    int w, int wp, int grp, int mtb, int lane, int n4, int q, int m0, int t,
    u16* h0s, u16* h1s, float* fcp, volatile int* sig0, volatile int* sig1,
    const float* sB, const float* sWx, const float* sFc,
    const u16* __restrict__ W0, const u16* __restrict__ W1h,
    const u16* __restrict__ W1x,
    short8 (&ah)[2][4], float2 (&xc)[2][4],
    floatx4 (&c0a)[2][4], floatx4 (&c1a)[2][4],
    float* __restrict__ out)
{
  const int bofs = DEC ? 1024 : 0;
  const int wxo  = DEC ? 512  : 0;
  const int lb = lane * 8;
  const int epoch = t + 1;

  // h1_old A-frags (own 2 mtiles, full K). Must be read before the flag0
  // signal: partner's h1 writes of this step are gated by our flag0.
  short8 a1[2][4];
  #pragma unroll
  for (int j = 0; j < 2; j++)
    #pragma unroll
    for (int c = 0; c < 4; c++)
      a1[j][c] = *(const short8*)(h1s + ((mtb+j)*4 + c)*512 + lb);

  // ---------------- cell 0: 4 slices (own N-half) ----------------------
  #pragma unroll 1
  for (int i = 0; i < 4; i++){
    const int s = grp*4 + i;
    const u16* bs = W0 + s*8192;
    short8 bw[16];
    #pragma unroll
    for (int k = 0; k < 16; k++)
      bw[k] = *(const short8*)(bs + k*512 + lb);
    floatx4 acc[4][2];
    #pragma unroll
    for (int g = 0; g < 4; g++){
      float bi = sB[bofs + g*128 + s*16 + n4];
      float2 wv = ((const float2*)sWx)[wxo + g*128 + s*16 + n4];
      #pragma unroll
      for (int j = 0; j < 2; j++)
        #pragma unroll
        for (int r = 0; r < 4; r++)
          acc[g][j][r] = fmaf(xc[j][r].y, wv.y, fmaf(xc[j][r].x, wv.x, bi));
    }
    __builtin_amdgcn_s_setprio(1);
    #pragma unroll
    for (int c = 0; c < 4; c++)
      #pragma unroll
      for (int g = 0; g < 4; g++){
        acc[g][0] = __builtin_amdgcn_mfma_f32_16x16x32_bf16(ah[0][c], bw[g*4+c], acc[g][0], 0,0,0);
        acc[g][1] = __builtin_amdgcn_mfma_f32_16x16x32_bf16(ah[1][c], bw[g*4+c], acc[g][1], 0,0,0);
      }
    __builtin_amdgcn_s_setprio(0);
    #pragma unroll
    for (int j = 0; j < 2; j++){
      const int hb = ((mtb+j)*4 + (s>>1))*512 + ((s&1)*2 + (n4>>3))*128 + q*32 + (n4&7);
      floatx4 cc = c0a[j][i], cn;
      float hv[4];
      #pragma unroll
      for (int r = 0; r < 4; r++){
        float ig = sigm2(acc[0][j][r]);
        float fg = sigm2(acc[1][j][r]);
        float gg = tanh2(acc[2][j][r]);
        float cv = fmaf(fg, cc[r], ig*gg);
        float og = sigm2(acc[3][j][r]);
        hv[r] = og * (1.f - 2.f*rcp_(1.f + exp2_(L2E2*cv)));
        cn[r] = cv;
      }
      u32 p01 = pk2bf(hv[0], hv[1]), p23 = pk2bf(hv[2], hv[3]);
      h0s[hb +  0] = (u16)p01;
      h0s[hb +  8] = (u16)(p01 >> 16);
      h0s[hb + 16] = (u16)p23;
      h0s[hb + 24] = (u16)(p23 >> 16);
      c0a[j][i] = cn;
    }
  }
  pair_sync(sig0, w, wp, epoch, lane);   // h0_new pairwise handoff

  // refresh ah = h0_new (also next step's h0_old frags)
  #pragma unroll
  for (int j = 0; j < 2; j++)
    #pragma unroll
    for (int c = 0; c < 4; c++)
      ah[j][c] = *(const short8*)(h0s + ((mtb+j)*4 + c)*512 + lb);

  float p[2][4][2];
  if (DEC){
    #pragma unroll
    for (int j = 0; j < 2; j++)
      #pragma unroll
      for (int r = 0; r < 4; r++){ p[j][r][0] = 0.f; p[j][r][1] = 0.f; }
  }

  // ---------------- cell 1: per slice, W1h x a1 then W1x x h0_new -------
  #pragma unroll 1
  for (int i = 0; i < 4; i++){
    const int s = grp*4 + i;
    floatx4 acc[4][2];
    #pragma unroll
    for (int g = 0; g < 4; g++){
      float bi = sB[bofs + 512 + g*128 + s*16 + n4];
      #pragma unroll
      for (int j = 0; j < 2; j++)
        #pragma unroll
        for (int r = 0; r < 4; r++) acc[g][j][r] = bi;
    }
    {
      const u16* bs = W1h + s*8192;
      short8 bw[16];
      #pragma unroll
      for (int k = 0; k < 16; k++)
        bw[k] = *(const short8*)(bs + k*512 + lb);
      __builtin_amdgcn_s_setprio(1);
      #pragma unroll
      for (int c = 0; c < 4; c++)
        #pragma unroll
        for (int g = 0; g < 4; g++){
          acc[g][0] = __builtin_amdgcn_mfma_f32_16x16x32_bf16(a1[0][c], bw[g*4+c], acc[g][0], 0,0,0);
          acc[g][1] = __builtin_amdgcn_mfma_f32_16x16x32_bf16(a1[1][c], bw[g*4+c], acc[g][1], 0,0,0);
        }
      __builtin_amdgcn_s_setprio(0);
    }
    {
      const u16* bs = W1x + s*8192;
      short8 bw[16];
      #pragma unroll
      for (int k = 0; k < 16; k++)
        bw[k] = *(const short8*)(bs + k*512 + lb);
      __builtin_amdgcn_s_setprio(1);
      #pragma unroll
      for (int c = 0; c < 4; c++)
        #pragma unroll
        for (int g = 0; g < 4; g++){
          acc[g][0] = __builtin_amdgcn_mfma_f32_16x16x32_bf16(ah[0][c], bw[g*4+c], acc[g][0], 0,0,0);
          acc[g][1] = __builtin_amdgcn_mfma_f32_16x16x32_bf16(ah[1][c], bw[g*4+c], acc[g][1], 0,0,0);
        }
      __builtin_amdgcn_s_setprio(0);
    }
    float f0 = 0.f, f1 = 0.f;
    if (DEC){ f0 = sFc[s*16 + n4]; f1 = sFc[128 + s*16 + n4]; }
    #pragma unroll
    for (int j = 0; j < 2; j++){
      const int hb = ((mtb+j)*4 + (s>>1))*512 + ((s&1)*2 + (n4>>3))*128 + q*32 + (n4&7);
      floatx4 cc = c1a[j][i], cn;
      float hv[4];
      #pragma unroll
      for (int r = 0; r < 4; r++){
        float ig = sigm2(acc[0][j][r]);
        float fg = sigm2(acc[1][j][r]);
        float gg = tanh2(acc[2][j][r]);
        float cv = fmaf(fg, cc[r], ig*gg);
        float og = sigm2(acc[3][j][r]);
        hv[r] = og * (1.f - 2.f*rcp_(1.f + exp2_(L2E2*cv)));
        cn[r] = cv;
        if (DEC){
          p[j][r][0] = fmaf(hv[r], f0, p[j][r][0]);
          p[j][r][1] = fmaf(hv[r], f1, p[j][r][1]);
        }
      }
      u32 p01 = pk2bf(hv[0], hv[1]), p23 = pk2bf(hv[2], hv[3]);
      h1s[hb +  0] = (u16)p01;
      h1s[hb +  8] = (u16)(p01 >> 16);
      h1s[hb + 16] = (u16)p23;
      h1s[hb + 24] = (u16)(p23 >> 16);
      c1a[j][i] = cn;
    }
  }

  if (DEC){
    // butterfly over n4 (16 lanes) -> per-group partial; stash pre-handshake
    #pragma unroll
    for (int off = 1; off < 16; off <<= 1)
      #pragma unroll
      for (int j = 0; j < 2; j++)
        #pragma unroll
        for (int r = 0; r < 4; r++){
          p[j][r][0] += __shfl_xor(p[j][r][0], off);
          p[j][r][1] += __shfl_xor(p[j][r][1], off);
        }
    if (n4 == 0){
      #pragma unroll
      for (int j = 0; j < 2; j++)
        #pragma unroll
        for (int r = 0; r < 4; r++){
          const int base = ((mtb+j)*16 + q*4 + r)*4 + grp*2;
          fcp[base + 0] = p[j][r][0];
          fcp[base + 1] = p[j][r][1];
        }
    }
  }
  pair_sync(sig1, w, wp, epoch, lane);   // h1_new + fcp pairwise handoff

  if (DEC){
    const float fb0 = sFc[256], fb1 = sFc[257];
    #pragma unroll
    for (int j = 0; j < 2; j++)
      #pragma unroll
      for (int r = 0; r < 4; r++){
        const int base = ((mtb+j)*16 + q*4 + r)*4;
        float2 pv;
        pv.x = fcp[base + 0] + fcp[base + 2] + fb0;
        pv.y = fcp[base + 1] + fcp[base + 3] + fb1;
        xc[j][r] = pv;
        if (grp == 0 && n4 == 0)
          *(float2*)(out + (long)(m0 + (mtb+j)*16 + q*4 + r)*90 + (t - 20)*2) = pv;
      }
  }
}

__global__ __launch_bounds__(512, 1) void lstm_all(
    const float* __restrict__ in_seq,
    const u16* __restrict__ wE0, const u16* __restrict__ wE1h, const u16* __restrict__ wE1x,
    const u16* __restrict__ wD0, const u16* __restrict__ wD1h, const u16* __restrict__ wD1x,
    const float* __restrict__ biasAll, const float* __restrict__ wxAll,
    const float* __restrict__ fcW, const float* __restrict__ fcb,
    float* __restrict__ out)
{
  __shared__ u16 h0s[16384];
  __shared__ u16 h1s[16384];
  __shared__ float sB[2048];
  __shared__ float sWx[2048];
  __shared__ float sFc[260];
  __shared__ float fcp[512];
  __shared__ int  sig[16];       // [0..7]=flag0, [8..15]=flag1

  const int tid = threadIdx.x, lane = tid & 63, w = tid >> 6;
  const int wp  = w ^ 1;               // partner wave (within-pair sync only)
  const int grp = w & 1, mtb = (w >> 1) * 2;
  const int n4 = lane & 15, q = lane >> 4;
  const int m0 = blockIdx.x * 128;

  for (int i = tid; i < 2048; i += 512){ sB[i] = biasAll[i]; sWx[i] = wxAll[i]; }
  if (tid < 258) sFc[tid] = (tid < 256) ? fcW[tid] : fcb[tid - 256];
  if (tid < 16) sig[tid] = 0;
  { u32* z0 = (u32*)h0s; u32* z1 = (u32*)h1s;
    for (int i = tid; i < 8192; i += 512){ z0[i] = 0u; z1[i] = 0u; } }

  floatx4 c0a[2][4], c1a[2][4];
  const floatx4 z4 = {0.f,0.f,0.f,0.f};
  #pragma unroll
  for (int j = 0; j < 2; j++)
    #pragma unroll
    for (int i = 0; i < 4; i++){ c0a[j][i] = z4; c1a[j][i] = z4; }
  __syncthreads();

  // prime h0_old frags (zeros); barrier orders these reads before step-0
  // writes from any wave
  short8 ah[2][4];
  #pragma unroll
  for (int j = 0; j < 2; j++)
    #pragma unroll
    for (int c = 0; c < 4; c++)
      ah[j][c] = *(const short8*)(h0s + ((mtb+j)*4 + c)*512 + lane*8);
  __syncthreads();

  // -------- cohort anti-phase skew: delay waves 4..7 (~10us, one-time). --
  // SIMD k hosts waves k and k+4; pairs (0,1),(2,3) vs (4,5),(6,7) are
  // mutually unsynced, so the offset persists and the two waves on each
  // SIMD interleave MFMA/VALU/load phases instead of stalling in unison.
  if (w >= 4){
    #pragma unroll 1
    for (int i = 0; i < 56; i++) __builtin_amdgcn_s_sleep(7);
  }

  float2 xc[2][4];

  // -------- encoder: t = 0..19 --------
  #pragma unroll 1
  for (int t = 0; t < 20; t++){
    #pragma unroll
    for (int j = 0; j < 2; j++)
      #pragma unroll
      for (int r = 0; r < 4; r++)
        xc[j][r] = *(const float2*)(in_seq + (long)(m0 + (mtb+j)*16 + q*4 + r)*40 + t*2);
    step_t<false>(w, wp, grp, mtb, lane, n4, q, m0, t, h0s, h1s, fcp,
                  sig, sig + 8, sB, sWx, sFc,
                  wE0, wE1h, wE1x, ah, xc, c0a, c1a, out);
  }

  // -------- decoder: t = 20..64, x fed back in registers --------
  #pragma unroll
  for (int j = 0; j < 2; j++)
    #pragma unroll
    for (int r = 0; r < 4; r++)
      xc[j][r] = *(const float2*)(in_seq + (long)(m0 + (mtb+j)*16 + q*4 + r)*40 + 38);

  #pragma unroll 1
  for (int t = 20; t < 65; t++){
    step_t<true>(w, wp, grp, mtb, lane, n4, q, m0, t, h0s, h1s, fcp,
                 sig, sig + 8, sB, sWx, sFc,
                 wD0, wD1h, wD1x, ah, xc, c0a, c1a, out);
  }
}

// ---------------- host ----------------
extern "C" void kernel_launch(void* const* d_in, const int* in_sizes, int n_in,
                              void* d_out, int out_size, void* d_ws, size_t ws_size,
                              hipStream_t stream)
{
  const float* in_seq = (const float*)d_in[0];
  const float* eWih0 = (const float*)d_in[1];
  const float* eWhh0 = (const float*)d_in[2];
  const float* ebih0 = (const float*)d_in[3];
  const float* ebhh0 = (const float*)d_in[4];
  const float* eWih1 = (const float*)d_in[5];
  const float* eWhh1 = (const float*)d_in[6];
  const float* ebih1 = (const float*)d_in[7];
  const float* ebhh1 = (const float*)d_in[8];
  const float* dWih0 = (const float*)d_in[9];
  const float* dWhh0 = (const float*)d_in[10];
  const float* dbih0 = (const float*)d_in[11];
  const float* dbhh0 = (const float*)d_in[12];
  const float* dWih1 = (const float*)d_in[13];
  const float* dWhh1 = (const float*)d_in[14];
  const float* dbih1 = (const float*)d_in[15];
  const float* dbhh1 = (const float*)d_in[16];
  const float* fcW   = (const float*)d_in[17];
  const float* fcb   = (const float*)d_in[18];
  float* out = (float*)d_out;
  char* ws = (char*)d_ws;

  u16* wE0   = (u16*)(ws + 0);                 // 128 KB each
  u16* wE1h  = (u16*)(ws + 131072);
  u16* wE1x  = (u16*)(ws + 262144);
  u16* wD0   = (u16*)(ws + 393216);
  u16* wD1h  = (u16*)(ws + 524288);
  u16* wD1x  = (u16*)(ws + 655360);
  float* biasAll = (float*)(ws + 786432);      // 8 KB
  float* wxAll   = (float*)(ws + 794624);      // 8 KB

  hipLaunchKernelGGL(prep_weights, dim3(1536), dim3(256), 0, stream,
                     eWhh0, eWhh1, eWih1, dWhh0, dWhh1, dWih1,
                     wE0, wE1h, wE1x, wD0, wD1h, wD1x);
  hipLaunchKernelGGL(prep_small, dim3(16), dim3(256), 0, stream,
                     ebih0, ebhh0, ebih1, ebhh1, dbih0, dbhh0, dbih1, dbhh1,
                     eWih0, dWih0, biasAll, wxAll);

  hipLaunchKernelGGL(lstm_all, dim3(256), dim3(512), 0, stream,
                     in_seq, (const u16*)wE0, (const u16*)wE1h, (const u16*)wE1x,
                     (const u16*)wD0, (const u16*)wD1h, (const u16*)wD1x,
                     (const float*)biasAll, (const float*)wxAll, fcW, fcb, out);
}